// Round 3
// baseline (304.913 us; speedup 1.0000x reference)
//
#include <hip/hip_runtime.h>
#include <hip/hip_bf16.h>

// Transposed conv (full conv): out[b,p,q,co] = sum_{kh,kw,ci} in[b,p-kh,q-kw,ci]*K[ci,co,kh,kw]
// B=8 H=W=256 C=64, out 8x258x258x64 fp32. bf16 MFMA path.
//
// R3 design: wave-autonomous, NO LDS, NO barrier. R1/R2 post-mortem: the
// stage->barrier->compute phase structure left the memory system idle ~75% of the
// time (MfmaUtil 13-15, VALUBusy 13, HBM 20%, occupancy didn't help). Here each
// wave owns a 4p x 16q x 64co output tile and streams A-fragments straight from
// global (coalesced 128B/16-lane group, f32->bf16 cvt in regs). Register cache:
// fragments indexed d = mt-kh (6 rows) are shared by up to 3 (mt,kh) pairs; kw
// shifts re-read via L1. Loads now spread uniformly through the kernel -> real MLP.
// Weight fragments read from global (pre-swizzled in d_ws, L1/L2-hot, same layout).

#define OH 258
#define OW 258

typedef __bf16 bf16x8 __attribute__((ext_vector_type(8)));
typedef float  f32x4  __attribute__((ext_vector_type(4)));

// ws layout: wsW[((tap*2+s)*64+co)*32 + c] = K[ci=32s+c][co][kh][kw], tap=kh*3+kw
// => fragment (tap,s,nt) is a contiguous 1KB block; lane (ml,h) reads ml*32+h*8.
__global__ void prep_w_kernel(const float* __restrict__ k, __bf16* __restrict__ wsW) {
    int i = blockIdx.x * 256 + threadIdx.x;            // [0, 36864)
    int c  = i & 31;
    int co = (i >> 5) & 63;
    int st = i >> 11;                                  // [0,18)
    int s   = st & 1;
    int tap = st >> 1;
    int kh = tap / 3, kw = tap % 3;
    float v = k[(s * 32 + c) * 576 + co * 9 + kh * 3 + kw];
    wsW[i] = (__bf16)v;
}

__global__ __launch_bounds__(256, 3)
void tconv_kernel(const float* __restrict__ in, const __bf16* __restrict__ wsW,
                  float* __restrict__ out) {
    const int tid = threadIdx.x;
    const int b  = blockIdx.z;
    const int p0 = blockIdx.y * 16;
    const int q0 = blockIdx.x * 16;

    const int wv = tid >> 6, lane = tid & 63;
    const int ml = lane & 15, h = lane >> 4;           // A: m=ml; B: n=ml; k-quad=h
    const int woff = ml * 32 + h * 8;                  // B-frag lane offset (elems)
    const int pw = p0 + wv * 4;                        // wave's first output row

    const float* inb = in + (size_t)b * (256 * 256 * 64);

    f32x4 acc[4][4] = {};   // mt = output row within wave's 4; nt = co/16

    #pragma unroll 1
    for (int kw = 0; kw < 3; ++kw) {
        const int iqk = q0 + ml - kw;                  // input col for this kw shift
        const bool qok = (unsigned)iqk < 256u;
        #pragma unroll
        for (int s = 0; s < 2; ++s) {
            // ---- 6 A-fragments: input rows pw-2 .. pw+3 (d = mt-kh+2)
            bf16x8 af[6];
            #pragma unroll
            for (int d = 0; d < 6; ++d) {
                const int ip = pw + d - 2;             // wave-uniform row
                f32x4 v0 = {0.f,0.f,0.f,0.f}, v1 = {0.f,0.f,0.f,0.f};
                if (qok && (unsigned)ip < 256u) {
                    const float* g = inb + ((size_t)(ip * 256 + iqk)) * 64
                                         + s * 32 + h * 8;
                    v0 = *(const f32x4*)g;
                    v1 = *(const f32x4*)(g + 4);
                }
                bf16x8 w;
                w[0]=(__bf16)v0[0]; w[1]=(__bf16)v0[1]; w[2]=(__bf16)v0[2]; w[3]=(__bf16)v0[3];
                w[4]=(__bf16)v1[0]; w[5]=(__bf16)v1[1]; w[6]=(__bf16)v1[2]; w[7]=(__bf16)v1[3];
                af[d] = w;
            }
            // ---- 3 kh taps: 4 B-frags each, 16 MFMA each
            #pragma unroll
            for (int kh = 0; kh < 3; ++kh) {
                const __bf16* wt = wsW + (kh * 3 + kw) * 4096 + s * 2048 + woff;
                bf16x8 bfr[4];
                #pragma unroll
                for (int nt = 0; nt < 4; ++nt)
                    bfr[nt] = *(const bf16x8*)(wt + nt * 512);
                #pragma unroll
                for (int mt = 0; mt < 4; ++mt) {
                    const bf16x8 a = af[mt - kh + 2];  // compile-time index
                    #pragma unroll
                    for (int nt = 0; nt < 4; ++nt)
                        acc[mt][nt] = __builtin_amdgcn_mfma_f32_16x16x32_bf16(
                            a, bfr[nt], acc[mt][nt], 0, 0, 0);
                }
            }
        }
    }

    // ---- epilogue: D layout col(co)=ml, row(q within row-tile)=h*4+reg
    #pragma unroll
    for (int mt = 0; mt < 4; ++mt) {
        int p = pw + mt;
        if (p < OH) {
            int qb = q0 + h * 4;
            #pragma unroll
            for (int nt = 0; nt < 4; ++nt) {
                float* op = out + (((size_t)b * OH + p) * OW + qb) * 64 + nt * 16 + ml;
                #pragma unroll
                for (int r = 0; r < 4; ++r)
                    if (qb + r < OW) op[(size_t)r * 64] = acc[mt][nt][r];
            }
        }
    }
}

extern "C" void kernel_launch(void* const* d_in, const int* in_sizes, int n_in,
                              void* d_out, int out_size, void* d_ws, size_t ws_size,
                              hipStream_t stream) {
    (void)in_sizes; (void)n_in; (void)out_size; (void)ws_size;
    const float* in   = (const float*)d_in[0];
    const float* kern = (const float*)d_in[1];
    float* out = (float*)d_out;
    __bf16* wsW = (__bf16*)d_ws;   // 36864 bf16 = 73728 B

    prep_w_kernel<<<144, 256, 0, stream>>>(kern, wsW);
    dim3 grid(17, 17, 8);          // q-tiles, p-tiles (16 rows each), batch
    tconv_kernel<<<grid, 256, 0, stream>>>(in, wsW, out);
}

// Round 4
// 257.314 us; speedup vs baseline: 1.1850x; 1.1850x over previous
//
#include <hip/hip_runtime.h>
#include <hip/hip_bf16.h>

// Transposed conv (full conv): out[b,p,q,co] = sum_{kh,kw,ci} in[b,p-kh,q-kw,ci]*K[ci,co,kh,kw]
// B=8 H=W=256 C=64, out 8x258x258x64 fp32. bf16 MFMA path.
//
// R4 design: R1's verified 32x16-tile structure, two fixes aimed at the weight-load
// stall that explains R1/R2/R3 all landing 120-150us (every wave re-read 72KB of
// weights from L2 inside the MFMA loop; ~300-450cy latency per (tap,s) step with
// only 16 MFMAs to cover it):
//   1. Weights staged to LDS once per block -> inner loop is pure ds_read+MFMA.
//      Block = 1024 thr / 16 waves (2 rows each), LDS = 78336(patch)+73728(wts)
//      = 148.5 KB, 1 block/CU, 4 waves/SIMD (same wave density as R1).
//   2. MFMA operands swapped -> D transposed (row=co, col=q): epilogue stores
//      f32x4 of consecutive co (global_store_dwordx4), 16 stores/thr vs 64.
// Fragment layouts, swizzle, and staging math identical to the verified R1 kernel.

#define OH 258
#define OW 258

typedef __bf16 bf16x8 __attribute__((ext_vector_type(8)));
typedef float  f32x4  __attribute__((ext_vector_type(4)));

// ws layout: wsW[((tap*2+s)*64+co)*32 + c] = K[ci=32s+c][co][kh][kw], tap=kh*3+kw
// => fragment (tap,s,nt) is a contiguous 1KB block; lane (ml,h) reads ml*32+h*8.
__global__ void prep_w_kernel(const float* __restrict__ k, __bf16* __restrict__ wsW) {
    int i = blockIdx.x * 256 + threadIdx.x;            // [0, 36864)
    int c  = i & 31;
    int co = (i >> 5) & 63;
    int st = i >> 11;                                  // [0,18)
    int s   = st & 1;
    int tap = st >> 1;
    int kh = tap / 3, kw = tap % 3;
    float v = k[(s * 32 + c) * 576 + co * 9 + kh * 3 + kw];
    wsW[i] = (__bf16)v;
}

__global__ __launch_bounds__(1024, 4)
void tconv_kernel(const float* __restrict__ in, const __bf16* __restrict__ wsW,
                  float* __restrict__ out) {
    // input patch [pix=34*18][64ci] bf16, 16B granules XOR-swizzled by pix&7
    __shared__ __bf16 lds_in[612 * 64];   // 78336 B
    __shared__ __bf16 lds_w[36864];       // 73728 B ; total 152064 B -> 1 block/CU

    const int tid = threadIdx.x;
    const int b  = blockIdx.z;
    const int p0 = blockIdx.y * 32;
    const int q0 = blockIdx.x * 16;

    // ---- stage input patch rows p0-2..p0+31, cols q0-2..q0+15; zero-pad OOB.
    // 612*8 = 4896 granules (granule = 8 ci), 1024 thr -> 4.78 iters.
    #pragma unroll 1
    for (int k = 0; k < 5; ++k) {
        const int it = tid + k * 1024;
        const bool act = (k < 4) || (tid < 800);       // it < 4896 (k compile-time)
        int pix = it >> 3, c8 = it & 7;
        int r = pix / 18, c = pix - r * 18;
        int ip = p0 - 2 + r, iq = q0 - 2 + c;
        f32x4 v0 = {0.f,0.f,0.f,0.f}, v1 = {0.f,0.f,0.f,0.f};
        if (act && (unsigned)ip < 256u && (unsigned)iq < 256u) {
            const float* g = in + (((size_t)b * 256 + ip) * 256 + iq) * 64 + c8 * 8;
            v0 = *(const f32x4*)g;
            v1 = *(const f32x4*)(g + 4);
        }
        if (act) {
            bf16x8 w;
            w[0]=(__bf16)v0[0]; w[1]=(__bf16)v0[1]; w[2]=(__bf16)v0[2]; w[3]=(__bf16)v0[3];
            w[4]=(__bf16)v1[0]; w[5]=(__bf16)v1[1]; w[6]=(__bf16)v1[2]; w[7]=(__bf16)v1[3];
            *(bf16x8*)&lds_in[pix * 64 + (c8 ^ (pix & 7)) * 8] = w;
        }
    }
    // ---- stage weights (already bf16, pre-swizzled, linear copy).
    // 36864 bf16 = 4608 granules of 16B, 1024 thr -> 4.5 iters.
    #pragma unroll
    for (int k = 0; k < 5; ++k) {
        const int g = tid + k * 1024;
        if ((k < 4) || (tid < 512))
            *(bf16x8*)&lds_w[(size_t)g * 8] = *(const bf16x8*)&wsW[(size_t)g * 8];
    }
    __syncthreads();   // the ONLY barrier

    const int wv = tid >> 6, lane = tid & 63;
    const int ml = lane & 15, h = lane >> 4;
    const int woff = ml * 32 + h * 8;      // weight frag: co=ml, ci-octet=h
    const int rbase = wv * 2;              // wave's 2 rows of the 32

    f32x4 acc[2][4] = {};   // mt = output row within wave's 2; nt = co/16

    #pragma unroll 1
    for (int tap = 0; tap < 9; ++tap) {
        const int kh = tap / 3, kw = tap - kh * 3;
        const __bf16* wt = lds_w + tap * 4096;
        #pragma unroll
        for (int s = 0; s < 2; ++s) {
            bf16x8 bfr[4];
            #pragma unroll
            for (int nt = 0; nt < 4; ++nt)
                bfr[nt] = *(const bf16x8*)(wt + s * 2048 + nt * 512 + woff);
            const int j = s * 4 + h;                   // 16B granule index within pixel
            #pragma unroll
            for (int mt = 0; mt < 2; ++mt) {
                int row = rbase + mt + 2 - kh;         // patch row, in [0,34)
                int pix = row * 18 + (2 - kw) + ml;    // pixel for q = q0+ml
                bf16x8 afr = *(const bf16x8*)&lds_in[pix * 64 + ((j ^ (pix & 7)) * 8)];
                #pragma unroll
                for (int nt = 0; nt < 4; ++nt)
                    acc[mt][nt] = __builtin_amdgcn_mfma_f32_16x16x32_bf16(
                        bfr[nt], afr, acc[mt][nt], 0, 0, 0);   // A=weights, B=pixels
            }
        }
    }

    // ---- epilogue: D transposed: row = co_local = h*4+reg, col = q_local = ml
    // lane (ml,h) holds out[p][q0+ml][nt*16 + h*4 + 0..3] -> contiguous dwordx4
    const int q = q0 + ml;
    #pragma unroll
    for (int mt = 0; mt < 2; ++mt) {
        int p = p0 + rbase + mt;
        if (p < OH && q < OW) {
            float* op = out + (((size_t)b * OH + p) * OW + q) * 64 + h * 4;
            #pragma unroll
            for (int nt = 0; nt < 4; ++nt)
                *(f32x4*)(op + nt * 16) = acc[mt][nt];
        }
    }
}

extern "C" void kernel_launch(void* const* d_in, const int* in_sizes, int n_in,
                              void* d_out, int out_size, void* d_ws, size_t ws_size,
                              hipStream_t stream) {
    (void)in_sizes; (void)n_in; (void)out_size; (void)ws_size;
    const float* in   = (const float*)d_in[0];
    const float* kern = (const float*)d_in[1];
    float* out = (float*)d_out;
    __bf16* wsW = (__bf16*)d_ws;   // 36864 bf16 = 73728 B

    prep_w_kernel<<<144, 256, 0, stream>>>(kern, wsW);
    dim3 grid(17, 9, 8);           // q-tiles, p-tiles (32 rows each), batch
    tconv_kernel<<<grid, 1024, 0, stream>>>(in, wsW, out);
}

// Round 5
// 251.554 us; speedup vs baseline: 1.2121x; 1.0229x over previous
//
#include <hip/hip_runtime.h>
#include <hip/hip_bf16.h>

// Transposed conv (full conv): out[b,p,q,co] = sum_{kh,kw,ci} in[b,p-kh,q-kw,ci]*K[ci,co,kh,kw]
// B=8 H=W=256 C=64, out 8x258x258x64 fp32. bf16 MFMA path.
//
// R5 design (from R4 post-mortem):
//  1. Weight LDS reads were 8-way bank-conflicted (5.64M cycles/dispatch): lane
//     stride was 64B. New wsW layout -> lane (ml,h) reads h*256+ml*16: each
//     16-lane group reads contiguous 256B = conflict-free b128.
//  2. Phase serialization at 1 block/CU: persistent 256-block grid (one per CU,
//     all resident), each block loops 4-5 tiles. Weights staged ONCE per block.
//     Per tile: barrier -> commit prefetch regs->LDS -> issue next tile's global
//     loads -> barrier -> compute (loads in flight under MFMA) -> store (T14).
// Fragment math, XOR patch swizzle, transposed-D dwordx4 epilogue = R4 (verified).

#define OH 258
#define OW 258

typedef __bf16 bf16x8 __attribute__((ext_vector_type(8)));
typedef float  f32x4  __attribute__((ext_vector_type(4)));

// ws layout (conflict-free): wsW[(((tap*2+s)*4+nt)*512) + h*128 + ml*8 + j]
//   = K[ci=32s+8h+j][co=16nt+ml][kh][kw],  tap=kh*3+kw
// => lane (ml,h) of frag (tap,s,nt) reads elems h*128+ml*8 .. +7 (bytes h*256+ml*16)
__global__ void prep_w_kernel(const float* __restrict__ k, __bf16* __restrict__ wsW) {
    int i = blockIdx.x * 256 + threadIdx.x;            // [0, 36864)
    int j  = i & 7;
    int ml = (i >> 3) & 15;
    int h  = (i >> 7) & 3;
    int nt = (i >> 9) & 3;
    int st = i >> 11;                                  // [0,18)
    int s  = st & 1, tap = st >> 1;
    int ci = s * 32 + h * 8 + j;
    int co = nt * 16 + ml;
    wsW[i] = (__bf16)k[ci * 576 + co * 9 + tap];
}

__device__ __forceinline__ void tile_coords(int tau, int& b, int& p0, int& q0) {
    int bb = tau / 153;                                // 153 = 9 p-tiles * 17 q-tiles
    int rr = tau - bb * 153;
    int py = rr / 17;
    b  = bb;
    p0 = py * 32;
    q0 = (rr - py * 17) * 16;
}

// issue the 10 guarded global loads for one tile's 34x18 patch into regs
__device__ __forceinline__ void issue_patch_loads(
        const float* __restrict__ in, int b, int p0, int q0, int tid,
        f32x4 (&v0)[5], f32x4 (&v1)[5]) {
    #pragma unroll
    for (int k = 0; k < 5; ++k) {
        const int it = tid + k * 1024;                 // granule id, < 4896
        const bool act = (k < 4) || (tid < 800);
        int pix = it >> 3, c8 = it & 7;
        int r = pix / 18, c = pix - r * 18;
        int ip = p0 - 2 + r, iq = q0 - 2 + c;
        f32x4 z = {0.f, 0.f, 0.f, 0.f};
        v0[k] = z; v1[k] = z;
        if (act && (unsigned)ip < 256u && (unsigned)iq < 256u) {
            const float* g = in + (((size_t)b * 256 + ip) * 256 + iq) * 64 + c8 * 8;
            v0[k] = *(const f32x4*)g;
            v1[k] = *(const f32x4*)(g + 4);
        }
    }
}

__global__ __launch_bounds__(1024, 4)
void tconv_kernel(const float* __restrict__ in, const __bf16* __restrict__ wsW,
                  float* __restrict__ out) {
    // input patch [pix=34*18][64ci] bf16, 16B granules XOR-swizzled by pix&7
    __shared__ __bf16 lds_in[612 * 64];   // 78336 B
    __shared__ __bf16 lds_w[36864];       // 73728 B ; 152064 total -> 1 block/CU

    const int tid = threadIdx.x;

    // ---- stage weights ONCE per block (linear bf16 copy, 4.5 iters)
    #pragma unroll
    for (int k = 0; k < 5; ++k) {
        const int g = tid + k * 1024;
        if ((k < 4) || (tid < 512))
            *(bf16x8*)&lds_w[(size_t)g * 8] = *(const bf16x8*)&wsW[(size_t)g * 8];
    }

    const int wv = tid >> 6, lane = tid & 63;
    const int ml = lane & 15, h = lane >> 4;
    const int woff = h * 128 + ml * 8;     // weight frag lane offset (conflict-free)
    const int rbase = wv * 2;              // wave's 2 rows of the 32

    // persistent: block bx handles tiles tau = bx + 256*t, tau < 1224
    const int bx = blockIdx.x;
    const int n_t = (bx < 200) ? 5 : 4;    // 200*5 + 56*4 = 1224

    int cb, cp0, cq0;
    tile_coords(bx, cb, cp0, cq0);
    f32x4 v0[5], v1[5];
    issue_patch_loads(in, cb, cp0, cq0, tid, v0, v1);  // tile 0 in flight

    int nb = 0, np0 = 0, nq0 = 0;

    #pragma unroll 1
    for (int t = 0; t < n_t; ++t) {
        __syncthreads();   // patch LDS free (prev compute done); weights committed
        // ---- commit prefetched regs -> LDS (cvt f32->bf16, swizzled write)
        #pragma unroll
        for (int k = 0; k < 5; ++k) {
            const int it = tid + k * 1024;
            if ((k < 4) || (tid < 800)) {
                int pix = it >> 3, c8 = it & 7;
                bf16x8 w;
                w[0]=(__bf16)v0[k][0]; w[1]=(__bf16)v0[k][1];
                w[2]=(__bf16)v0[k][2]; w[3]=(__bf16)v0[k][3];
                w[4]=(__bf16)v1[k][0]; w[5]=(__bf16)v1[k][1];
                w[6]=(__bf16)v1[k][2]; w[7]=(__bf16)v1[k][3];
                *(bf16x8*)&lds_in[pix * 64 + ((c8 ^ (pix & 7)) * 8)] = w;
            }
        }
        // ---- issue NEXT tile's global loads; they fly under this tile's compute
        if (t + 1 < n_t) {
            tile_coords(bx + (t + 1) * 256, nb, np0, nq0);
            issue_patch_loads(in, nb, np0, nq0, tid, v0, v1);
        }
        __syncthreads();   // patch ready

        // ---- compute: pure ds_read + MFMA (A=weights, B=pixels -> D transposed)
        f32x4 acc[2][4] = {};   // mt = output row within wave's 2; nt = co/16
        #pragma unroll 1
        for (int tap = 0; tap < 9; ++tap) {
            const int kh = tap / 3, kw = tap - kh * 3;
            const __bf16* wt = lds_w + tap * 4096;
            #pragma unroll
            for (int s = 0; s < 2; ++s) {
                bf16x8 bfr[4];
                #pragma unroll
                for (int nt = 0; nt < 4; ++nt)
                    bfr[nt] = *(const bf16x8*)(wt + s * 2048 + nt * 512 + woff);
                const int j = s * 4 + h;               // 16B granule within pixel
                #pragma unroll
                for (int mt = 0; mt < 2; ++mt) {
                    int row = rbase + mt + 2 - kh;     // patch row, in [0,34)
                    int pix = row * 18 + (2 - kw) + ml;
                    bf16x8 afr = *(const bf16x8*)&lds_in[pix * 64 + ((j ^ (pix & 7)) * 8)];
                    #pragma unroll
                    for (int nt = 0; nt < 4; ++nt)
                        acc[mt][nt] = __builtin_amdgcn_mfma_f32_16x16x32_bf16(
                            bfr[nt], afr, acc[mt][nt], 0, 0, 0);
                }
            }
        }

        // ---- epilogue: D transposed: lane (ml,h) holds out[p][cq0+ml][nt*16+h*4..+3]
        const int q = cq0 + ml;
        #pragma unroll
        for (int mt = 0; mt < 2; ++mt) {
            int p = cp0 + rbase + mt;
            if (p < OH && q < OW) {
                float* op = out + (((size_t)cb * OH + p) * OW + q) * 64 + h * 4;
                #pragma unroll
                for (int nt = 0; nt < 4; ++nt)
                    *(f32x4*)(op + nt * 16) = acc[mt][nt];
            }
        }
        cb = nb; cp0 = np0; cq0 = nq0;
    }
}

extern "C" void kernel_launch(void* const* d_in, const int* in_sizes, int n_in,
                              void* d_out, int out_size, void* d_ws, size_t ws_size,
                              hipStream_t stream) {
    (void)in_sizes; (void)n_in; (void)out_size; (void)ws_size;
    const float* in   = (const float*)d_in[0];
    const float* kern = (const float*)d_in[1];
    float* out = (float*)d_out;
    __bf16* wsW = (__bf16*)d_ws;   // 36864 bf16 = 73728 B

    prep_w_kernel<<<144, 256, 0, stream>>>(kern, wsW);
    tconv_kernel<<<256, 1024, 0, stream>>>(in, wsW, out);
}